// Round 4
// baseline (1170.421 us; speedup 1.0000x reference)
//
#include <hip/hip_runtime.h>
#include <hip/hip_bf16.h>

typedef __attribute__((ext_vector_type(8))) short short8;
typedef __attribute__((ext_vector_type(4))) float floatx4;
typedef __attribute__((ext_vector_type(8))) unsigned short ushortx8;

__device__ __forceinline__ float b2f(unsigned short u) {
    return __uint_as_float(((unsigned int)u) << 16);
}
__device__ __forceinline__ unsigned short f2b(float f) {
    __hip_bfloat16 b = __float2bfloat16(f);
    return *(unsigned short*)&b;
}
// elu(leaky_relu(x, 0.2)): x>=0 -> x ; x<0 -> expm1(0.2x) ~= exp(0.2x)-1
__device__ __forceinline__ float act_elu_lrelu(float x) {
    return x >= 0.f ? x : (__expf(0.2f * x) - 1.f);
}

// async global->LDS 16B per lane; dest is wave-uniform base + lane*16
__device__ __forceinline__ void gload16(const void* g, void* l) {
    __builtin_amdgcn_global_load_lds(
        (__attribute__((address_space(1))) void*)(g),
        (__attribute__((address_space(3))) void*)(l), 16, 0, 0);
}
#define SB() __builtin_amdgcn_sched_barrier(0)
#define WAITVM(n)                                               \
    do {                                                        \
        asm volatile("s_waitcnt vmcnt(" #n ")" ::: "memory");   \
        __builtin_amdgcn_sched_barrier(0);                      \
    } while (0)

// ---------------------------------------------------------------------------
// row_ptr build from sorted adj_row
// ---------------------------------------------------------------------------
__global__ void build_rowptr(const int* __restrict__ row, int* __restrict__ rp,
                             int E, int N) {
    int e = blockIdx.x * blockDim.x + threadIdx.x;
    if (e >= E) return;
    int r = row[e];
    int rprev = (e == 0) ? -1 : row[e - 1];
    for (int q = rprev + 1; q <= r; ++q) rp[q] = e;
    if (e == E - 1) {
        for (int q = r + 1; q <= N; ++q) rp[q] = E;
    }
}

// ---------------------------------------------------------------------------
// Degree-binned node permutation: hist -> scan -> scatter
// ---------------------------------------------------------------------------
__global__ __launch_bounds__(256) void deg_hist(const int* __restrict__ rp,
                                                int* __restrict__ hist, int N) {
    int n = blockIdx.x * 256 + threadIdx.x;
    if (n >= N) return;
    int d = rp[n + 1] - rp[n];
    atomicAdd(&hist[d < 255 ? d : 255], 1);
}

__global__ __launch_bounds__(256) void scan256(const int* __restrict__ hist,
                                               int* __restrict__ binCur) {
    __shared__ int tmp[256];
    int t = threadIdx.x;
    int v = hist[t];
    tmp[t] = v;
    __syncthreads();
    for (int o = 1; o < 256; o <<= 1) {
        int u = (t >= o) ? tmp[t - o] : 0;
        __syncthreads();
        tmp[t] += u;
        __syncthreads();
    }
    binCur[t] = tmp[t] - v;  // exclusive
}

__global__ __launch_bounds__(256) void deg_scatter(const int* __restrict__ rp,
                                                   int* __restrict__ binCur,
                                                   int* __restrict__ perm,
                                                   int N) {
    int n = blockIdx.x * 256 + threadIdx.x;
    if (n >= N) return;
    int d = rp[n + 1] - rp[n];
    int pos = atomicAdd(&binCur[d < 255 ? d : 255], 1);
    perm[pos] = n;
}

// Per-16-group uniform padded length L + base carve (atomic bump allocator)
__global__ __launch_bounds__(256) void grp_len(
    const int* __restrict__ rp, const int* __restrict__ perm,
    int* __restrict__ gL, int* __restrict__ gBase, int* __restrict__ cnt,
    int N, int ngroups) {
    int gi = blockIdx.x * 256 + threadIdx.x;
    if (gi >= ngroups) return;
    int m = 0;
    for (int j = 0; j < 16; ++j) {
        int p = gi * 16 + j;
        if (p < N) {
            int n = perm[p];
            int d = rp[n + 1] - rp[n];
            m = m > d ? m : d;
        }
    }
    int L = (m + 3) & ~3;
    gL[gi] = L;
    gBase[gi] = L ? atomicAdd(cnt, 16 * L) : 0;
}

// Fill padded packed edge array: one WAVE per perm-position, {col,val} pairs,
// zero-padded to L.
__global__ __launch_bounds__(256) void fill_packed(
    const int* __restrict__ rp, const int* __restrict__ colIdx,
    const float* __restrict__ vals, const int* __restrict__ perm,
    const int* __restrict__ gL, const int* __restrict__ gBase,
    float2* __restrict__ packed, int N, int Npos) {
    int w = (blockIdx.x * 256 + threadIdx.x) >> 6;
    int lane = threadIdx.x & 63;
    if (w >= Npos) return;
    int gi = w >> 4;
    int L = gL[gi];
    if (L == 0) return;
    float2* dst = packed + (size_t)gBase[gi] + (size_t)(w & 15) * L;
    int d = 0, e0 = 0;
    if (w < N) {
        int n = perm[w];
        e0 = rp[n];
        d = rp[n + 1] - e0;
    }
    for (int j = lane; j < L; j += 64) {
        float2 v;
        if (j < d) {
            v.x = __int_as_float(colIdx[e0 + j]);
            v.y = vals[e0 + j];
        } else {
            v.x = __int_as_float(0);
            v.y = 0.f;
        }
        dst[j] = v;
    }
}

// ---------------------------------------------------------------------------
// One-shot W prep: all four W's -> bf16, transposed + XOR-swizzled.
// Layout: Wb[(n * (CIN/8) + (kc ^ (n&7))) * 8 + kr],  k = kc*8 + kr
// ---------------------------------------------------------------------------
__global__ __launch_bounds__(256) void wprep(
    const float* __restrict__ W1, const float* __restrict__ W2,
    const float* __restrict__ W3, const float* __restrict__ W4,
    unsigned short* __restrict__ B1, unsigned short* __restrict__ B2,
    unsigned short* __restrict__ B3, unsigned short* __restrict__ B4) {
    int i = blockIdx.x * 256 + threadIdx.x;
    const float* W;
    unsigned short* Wb;
    int CIN, COUT, idx;
    if (i < 32768) {
        W = W1; Wb = B1; CIN = 256; COUT = 128; idx = i;
    } else if (i < 49152) {
        W = W2; Wb = B2; CIN = 128; COUT = 128; idx = i - 32768;
    } else if (i < 57344) {
        W = W3; Wb = B3; CIN = 128; COUT = 64; idx = i - 49152;
    } else if (i < 59392) {
        W = W4; Wb = B4; CIN = 64; COUT = 32; idx = i - 57344;
    } else {
        return;
    }
    int k = idx / COUT, n = idx % COUT;
    int kc = k >> 3, kr = k & 7;
    Wb[((size_t)n * (CIN / 8) + (kc ^ (n & 7))) * 8 + kr] =
        (unsigned short)f2b(W[idx]);
}

// ---------------------------------------------------------------------------
// MFMA GEMM with fused input-BN. 256 threads, 64 rows/block.
// W staged in TWO COUT-halves (halves LDS -> more blocks/CU).
// ---------------------------------------------------------------------------
template <int CIN, int COUT, bool NORM>
__global__ __launch_bounds__(256) void gemm_mfma(
    float* H, const unsigned short* __restrict__ Wb,
    unsigned short* __restrict__ S, const float* __restrict__ st, float invN,
    int Nrows) {
    constexpr int CHALF = COUT / 2;
    constexpr int NCHUNK = CIN / 8;
    __shared__ short Wt[CIN * CHALF];

    int wave = threadIdx.x >> 6, lane = threadIdx.x & 63;
    int m = lane & 15, quad = lane >> 4;
    int r0 = blockIdx.x * 64 + wave * 16;
    int rowi = r0 + m;
    int rowc = rowi < Nrows ? rowi : (Nrows - 1);

    short8 a[CIN / 32];
    const float* hrow = H + (size_t)rowc * CIN;
#pragma unroll
    for (int ks = 0; ks < CIN / 32; ++ks) {
        int c0 = ks * 32 + quad * 8;
        const float* p = hrow + c0;
        floatx4 x0 = *(const floatx4*)p;
        floatx4 x1 = *(const floatx4*)(p + 4);
        if constexpr (NORM) {
            floatx4 s0 = *(const floatx4*)(st + c0);
            floatx4 s1 = *(const floatx4*)(st + c0 + 4);
            floatx4 q0 = *(const floatx4*)(st + CIN + c0);
            floatx4 q1 = *(const floatx4*)(st + CIN + c0 + 4);
#pragma unroll
            for (int j = 0; j < 4; ++j) {
                float mean = s0[j] * invN;
                float var = q0[j] * invN - mean * mean;
                x0[j] = (x0[j] - mean) * rsqrtf(fmaxf(var, 0.f) + 1e-5f);
                mean = s1[j] * invN;
                var = q1[j] * invN - mean * mean;
                x1[j] = (x1[j] - mean) * rsqrtf(fmaxf(var, 0.f) + 1e-5f);
            }
            if (rowi < Nrows) {
                float* op = H + (size_t)rowi * CIN + c0;
                __builtin_nontemporal_store(x0, (floatx4*)op);
                __builtin_nontemporal_store(x1, (floatx4*)(op + 4));
            }
        }
        short8 t;
#pragma unroll
        for (int j = 0; j < 4; ++j) {
            t[j] = (short)f2b(x0[j]);
            t[4 + j] = (short)f2b(x1[j]);
        }
        a[ks] = t;
    }

#pragma unroll
    for (int h = 0; h < 2; ++h) {
        {
            constexpr int CHUNKS = CIN * CHALF / 8;  // short8 chunks
            const short8* src = (const short8*)(Wb + h * CIN * CHALF);
            short8* dst = (short8*)Wt;
            for (int i = threadIdx.x; i < CHUNKS; i += 256) dst[i] = src[i];
        }
        __syncthreads();

#pragma unroll
        for (int nt = 0; nt < CHALF / 16; ++nt) {
            floatx4 acc = {0.f, 0.f, 0.f, 0.f};
            int nn = nt * 16 + m;  // local col within half
#pragma unroll
            for (int ks = 0; ks < CIN / 32; ++ks) {
                int kc = ks * 4 + quad;
                short8 b =
                    *(const short8*)(&Wt[(nn * NCHUNK + (kc ^ (nn & 7))) * 8]);
                acc = __builtin_amdgcn_mfma_f32_16x16x32_bf16(a[ks], b, acc, 0,
                                                              0, 0);
            }
            int n = h * CHALF + nn;
#pragma unroll
            for (int reg = 0; reg < 4; ++reg) {
                int rr = r0 + quad * 4 + reg;
                if (rr < Nrows) S[(size_t)rr * COUT + n] = f2b(acc[reg]);
            }
        }
        __syncthreads();
    }
}

// ---------------------------------------------------------------------------
// SpMM + activation + fused BN stats on the padded/binned edge layout.
// Wave-uniform row length (per 16-group), packed {col,val} 8B stream,
// zero clamps/selects. 2-slot wave-private LDS pipeline w/ counted vmcnt.
// ---------------------------------------------------------------------------
template <int C>
__global__ __launch_bounds__(256) void spmm_act_stats(
    const char* __restrict__ Sb, const float2* __restrict__ packed,
    const int* __restrict__ gBase, const int* __restrict__ gL,
    const int* __restrict__ perm, float* __restrict__ Ag,
    float* __restrict__ stats, int N, int Npos) {
    constexpr int LPN = C / 8;      // lanes per node
    constexpr int NPB = 256 / LPN;  // positions per block
    constexpr int SH = (C == 128) ? 8 : (C == 64) ? 7 : 6;  // row byte shift
    __shared__ __align__(16) char stage[4 * 2 * 4096];  // 4 waves x 2 slots

    int tid = threadIdx.x;
    int wave = tid >> 6, lane = tid & 63;
    int sub = tid / LPN, lc = tid % LPN;
    char* wbase = stage + wave * 8192;
    int lcoff = lc * 16;

    float s[8], s2[8];
#pragma unroll
    for (int j = 0; j < 8; ++j) { s[j] = 0.f; s2[j] = 0.f; }

    int nblk = (Npos + NPB - 1) / NPB;
    for (int blk = blockIdx.x; blk < nblk; blk += gridDim.x) {
        int p = blk * NPB + sub;
        int inb = p < Npos;                 // uniform per wave (16-aligned)
        int gi = inb ? (p >> 4) : 0;
        int L = inb ? gL[gi] : 0;           // uniform per wave
        float acc[8];
#pragma unroll
        for (int j = 0; j < 8; ++j) acc[j] = 0.f;

        if (L) {
            const float2* pe =
                packed + (size_t)gBase[gi] + (size_t)(p & 15) * L;
            int tmax = L >> 2;

            // prologue: pkA = batch0, pkB = batch1, issue gathers0 -> slot0
            float2 pkA[4], pkB[4];
#pragma unroll
            for (int k = 0; k < 4; ++k) pkA[k] = pe[k];
#pragma unroll
            for (int k = 0; k < 4; ++k) pkB[k] = pe[4 + k];
            SB();
#pragma unroll
            for (int k = 0; k < 4; ++k)
                gload16(Sb + (((unsigned)__float_as_uint(pkA[k].x) << SH) +
                              lcoff),
                        wbase + k * 1024);
            SB();

            // steady: iter t computes batch t, prefetches pk[t+2], gathers[t+1]
            for (int t = 0; t < tmax - 1; ++t) {
                int slot = t & 1;
                float2 pkC[4];
                const float2* pe2 = pe + t * 4 + 8;
#pragma unroll
                for (int k = 0; k < 4; ++k) pkC[k] = pe2[k];
                SB();
                WAITVM(8);  // retire pk[t+1] (pkB); gathers[t] still in flight
                char* dst = wbase + (slot ^ 1) * 4096;
#pragma unroll
                for (int k = 0; k < 4; ++k)
                    gload16(Sb + (((unsigned)__float_as_uint(pkB[k].x) << SH) +
                                  lcoff),
                            dst + k * 1024);
                SB();
                WAITVM(8);  // retire gathers[t]; {pkC, gathers[t+1]} in flight
                const char* src = wbase + slot * 4096 + lane * 16;
#pragma unroll
                for (int k = 0; k < 4; ++k) {
                    ushortx8 gk = *(const ushortx8*)(src + k * 1024);
                    float v = pkA[k].y;
#pragma unroll
                    for (int j = 0; j < 8; ++j) acc[j] += v * b2f(gk[j]);
                }
#pragma unroll
                for (int k = 0; k < 4; ++k) { pkA[k] = pkB[k]; pkB[k] = pkC[k]; }
            }

            // tail: compute last batch
            WAITVM(0);
            {
                int slot = (tmax - 1) & 1;
                const char* src = wbase + slot * 4096 + lane * 16;
#pragma unroll
                for (int k = 0; k < 4; ++k) {
                    ushortx8 gk = *(const ushortx8*)(src + k * 1024);
                    float v = pkA[k].y;
#pragma unroll
                    for (int j = 0; j < 8; ++j) acc[j] += v * b2f(gk[j]);
                }
            }
        }

        if (p < N) {
            int node = perm[p];
            floatx4 r0, r1;
#pragma unroll
            for (int j = 0; j < 4; ++j) {
                float a0 = act_elu_lrelu(acc[j]);
                float a1 = act_elu_lrelu(acc[4 + j]);
                r0[j] = a0;
                r1[j] = a1;
                s[j] += a0;
                s2[j] += a0 * a0;
                s[4 + j] += a1;
                s2[4 + j] += a1 * a1;
            }
            float* op = Ag + (size_t)node * C + lc * 8;
            *(floatx4*)op = r0;
            *(floatx4*)(op + 4) = r1;
        }
    }

    // block-level column reduce (reuse staging LDS; all waves done)
    __syncthreads();
    float* sh = (float*)stage;  // [2][NPB][C] = 16KB <= 32KB
#pragma unroll
    for (int j = 0; j < 8; ++j) {
        sh[(0 * NPB + sub) * C + lc * 8 + j] = s[j];
        sh[(1 * NPB + sub) * C + lc * 8 + j] = s2[j];
    }
    __syncthreads();
    if (tid < C) {
        float t0 = 0.f, t1 = 0.f;
        for (int gg = 0; gg < NPB; ++gg) {
            t0 += sh[(0 * NPB + gg) * C + tid];
            t1 += sh[(1 * NPB + gg) * C + tid];
        }
        atomicAdd(&stats[tid], t0);
        atomicAdd(&stats[C + tid], t1);
    }
}

// ---------------------------------------------------------------------------
// Final-layer BN normalize in place
// ---------------------------------------------------------------------------
template <int C>
__global__ __launch_bounds__(256) void bn_norm(
    float* __restrict__ Ag, const float* __restrict__ stats, int N) {
    constexpr int RPB = 256 / C;
    int c = threadIdx.x % C;
    int rg = threadIdx.x / C;
    float invN = 1.f / (float)N;
    float mean = stats[c] * invN;
    float var = stats[C + c] * invN - mean * mean;
    float inv = rsqrtf(fmaxf(var, 0.f) + 1e-5f);
    for (int r = blockIdx.x * RPB + rg; r < N; r += gridDim.x * RPB) {
        float x = Ag[(size_t)r * C + c];
        Ag[(size_t)r * C + c] = (x - mean) * inv;
    }
}

// ---------------------------------------------------------------------------
extern "C" void kernel_launch(void* const* d_in, const int* in_sizes, int n_in,
                              void* d_out, int out_size, void* d_ws,
                              size_t ws_size, hipStream_t stream) {
    const float* x = (const float*)d_in[0];
    const int* adj_row = (const int*)d_in[1];
    const int* adj_col = (const int*)d_in[2];
    const float* adj_vals = (const float*)d_in[3];
    const float* W1 = (const float*)d_in[4];
    const float* W2 = (const float*)d_in[5];
    const float* W3 = (const float*)d_in[6];
    const float* W4 = (const float*)d_in[7];

    int N = in_sizes[0] / 256;
    int E = in_sizes[1];
    int ngroups = (N + 15) / 16;
    int Npos = ngroups * 16;

    // workspace carve
    char* ws = (char*)d_ws;
    size_t off = 0;
    auto carve = [&](size_t bytes) {
        char* p = ws + off;
        off = (off + bytes + 255) & ~(size_t)255;
        return p;
    };
    int* rp = (int*)carve((size_t)(N + 1) * 4);
    // contiguous memset region: stats(1024f) + hist(256i) + cnt(64i)
    float* stats = (float*)carve((1024 + 256 + 64) * 4);
    int* hist = (int*)((char*)stats + 1024 * 4);
    int* cnt = hist + 256;
    int* binCur = (int*)carve(256 * 4);
    unsigned short* Wb1 = (unsigned short*)carve(32768 * 2);
    unsigned short* Wb2 = (unsigned short*)carve(16384 * 2);
    unsigned short* Wb3 = (unsigned short*)carve(8192 * 2);
    unsigned short* Wb4 = (unsigned short*)carve(2048 * 2);
    int* perm = (int*)carve((size_t)Npos * 4);
    int* gL = (int*)carve((size_t)ngroups * 4);
    int* gBase = (int*)carve((size_t)ngroups * 4);
    float2* packed = (float2*)carve(((size_t)E + 4 * (size_t)N + 2048) * 8);
    unsigned short* S = (unsigned short*)carve((size_t)N * 128 * 2);

    hipMemsetAsync(stats, 0, (1024 + 256 + 64) * 4, stream);
    build_rowptr<<<(E + 255) / 256, 256, 0, stream>>>(adj_row, rp, E, N);
    wprep<<<232, 256, 0, stream>>>(W1, W2, W3, W4, Wb1, Wb2, Wb3, Wb4);
    int nb = (N + 255) / 256;
    deg_hist<<<nb, 256, 0, stream>>>(rp, hist, N);
    scan256<<<1, 256, 0, stream>>>(hist, binCur);
    deg_scatter<<<nb, 256, 0, stream>>>(rp, binCur, perm, N);
    grp_len<<<(ngroups + 255) / 256, 256, 0, stream>>>(rp, perm, gL, gBase,
                                                       cnt, N, ngroups);
    fill_packed<<<(Npos + 3) / 4, 256, 0, stream>>>(
        rp, adj_col, adj_vals, perm, gL, gBase, packed, N, Npos);

    float* h1 = (float*)d_out;
    float* h2 = h1 + (size_t)N * 128;
    float* h3 = h2 + (size_t)N * 128;
    float* h4 = h3 + (size_t)N * 64;

    float invN = 1.f / (float)N;
    int gblk = (N + 63) / 64;
    auto sgrid = [&](int npb) {
        int ng = (Npos + npb - 1) / npb;
        return ng < 2048 ? ng : 2048;
    };

    // layer 1: 256 -> 128 (input x is not normalized)
    gemm_mfma<256, 128, false><<<gblk, 256, 0, stream>>>(
        (float*)x, Wb1, S, nullptr, invN, N);
    spmm_act_stats<128><<<sgrid(16), 256, 0, stream>>>(
        (const char*)S, packed, gBase, gL, perm, h1, stats + 0, N, Npos);

    // layer 2: 128 -> 128 (gemm normalizes h1 in place using stats0)
    gemm_mfma<128, 128, true><<<gblk, 256, 0, stream>>>(
        h1, Wb2, S, stats + 0, invN, N);
    spmm_act_stats<128><<<sgrid(16), 256, 0, stream>>>(
        (const char*)S, packed, gBase, gL, perm, h2, stats + 256, N, Npos);

    // layer 3: 128 -> 64
    gemm_mfma<128, 64, true><<<gblk, 256, 0, stream>>>(
        h2, Wb3, S, stats + 256, invN, N);
    spmm_act_stats<64><<<sgrid(32), 256, 0, stream>>>(
        (const char*)S, packed, gBase, gL, perm, h3, stats + 512, N, Npos);

    // layer 4: 64 -> 32
    gemm_mfma<64, 32, true><<<gblk, 256, 0, stream>>>(
        h3, Wb4, S, stats + 512, invN, N);
    spmm_act_stats<32><<<sgrid(64), 256, 0, stream>>>(
        (const char*)S, packed, gBase, gL, perm, h4, stats + 768, N, Npos);
    bn_norm<32><<<256, 256, 0, stream>>>(h4, stats + 768, N);
}

// Round 5
// 659.543 us; speedup vs baseline: 1.7746x; 1.7746x over previous
//
#include <hip/hip_runtime.h>
#include <hip/hip_bf16.h>

typedef __attribute__((ext_vector_type(8))) short short8;
typedef __attribute__((ext_vector_type(4))) float floatx4;
typedef __attribute__((ext_vector_type(8))) unsigned short ushortx8;

__device__ __forceinline__ float b2f(unsigned short u) {
    return __uint_as_float(((unsigned int)u) << 16);
}
__device__ __forceinline__ unsigned short f2b(float f) {
    __hip_bfloat16 b = __float2bfloat16(f);
    return *(unsigned short*)&b;
}
// elu(leaky_relu(x, 0.2)): x>=0 -> x ; x<0 -> expm1(0.2x) ~= exp(0.2x)-1
__device__ __forceinline__ float act_elu_lrelu(float x) {
    return x >= 0.f ? x : (__expf(0.2f * x) - 1.f);
}

// async global->LDS 16B per lane; dest is wave-uniform base + lane*16
__device__ __forceinline__ void gload16(const void* g, void* l) {
    __builtin_amdgcn_global_load_lds(
        (__attribute__((address_space(1))) void*)(g),
        (__attribute__((address_space(3))) void*)(l), 16, 0, 0);
}
#define SB() __builtin_amdgcn_sched_barrier(0)
#define WAITVM(n)                                               \
    do {                                                        \
        asm volatile("s_waitcnt vmcnt(" #n ")" ::: "memory");   \
        __builtin_amdgcn_sched_barrier(0);                      \
    } while (0)

// ---------------------------------------------------------------------------
// row_ptr build from sorted adj_row
// ---------------------------------------------------------------------------
__global__ void build_rowptr(const int* __restrict__ row, int* __restrict__ rp,
                             int E, int N) {
    int e = blockIdx.x * blockDim.x + threadIdx.x;
    if (e >= E) return;
    int r = row[e];
    int rprev = (e == 0) ? -1 : row[e - 1];
    for (int q = rprev + 1; q <= r; ++q) rp[q] = e;
    if (e == E - 1) {
        for (int q = r + 1; q <= N; ++q) rp[q] = E;
    }
}

// ---------------------------------------------------------------------------
// Degree histogram: block-local LDS hist -> one global atomic per nonzero bin
// (avoids the 10K-deep same-address global atomic queues of the naive form)
// ---------------------------------------------------------------------------
__global__ __launch_bounds__(256) void deg_hist(const int* __restrict__ rp,
                                                int* __restrict__ hist, int N) {
    __shared__ int lh[256];
    lh[threadIdx.x] = 0;
    __syncthreads();
    int n = blockIdx.x * 256 + threadIdx.x;
    if (n < N) {
        int d = rp[n + 1] - rp[n];
        atomicAdd(&lh[d < 255 ? d : 255], 1);
    }
    __syncthreads();
    int v = lh[threadIdx.x];
    if (v) atomicAdd(&hist[threadIdx.x], v);
}

__global__ __launch_bounds__(256) void scan256(const int* __restrict__ hist,
                                               int* __restrict__ binCur) {
    __shared__ int tmp[256];
    int t = threadIdx.x;
    int v = hist[t];
    tmp[t] = v;
    __syncthreads();
    for (int o = 1; o < 256; o <<= 1) {
        int u = (t >= o) ? tmp[t - o] : 0;
        __syncthreads();
        tmp[t] += u;
        __syncthreads();
    }
    binCur[t] = tmp[t] - v;  // exclusive
}

// Scatter: LDS atomic gives within-block rank; one global atomic per nonzero
// bin reserves the block's span in that bin.
__global__ __launch_bounds__(256) void deg_scatter(const int* __restrict__ rp,
                                                   int* __restrict__ binCur,
                                                   int* __restrict__ perm,
                                                   int N) {
    __shared__ int lh[256];
    lh[threadIdx.x] = 0;
    __syncthreads();
    int n = blockIdx.x * 256 + threadIdx.x;
    int d = 0, rank = 0;
    if (n < N) {
        int dd = rp[n + 1] - rp[n];
        d = dd < 255 ? dd : 255;
        rank = atomicAdd(&lh[d], 1);
    }
    __syncthreads();
    int c = lh[threadIdx.x];
    __syncthreads();
    if (c) lh[threadIdx.x] = atomicAdd(&binCur[threadIdx.x], c);
    __syncthreads();
    if (n < N) perm[lh[d] + rank] = n;
}

// Per-16-group uniform padded length L + base carve (atomic bump allocator)
__global__ __launch_bounds__(256) void grp_len(
    const int* __restrict__ rp, const int* __restrict__ perm,
    int* __restrict__ gL, int* __restrict__ gBase, int* __restrict__ cnt,
    int N, int ngroups) {
    int gi = blockIdx.x * 256 + threadIdx.x;
    if (gi >= ngroups) return;
    int m = 0;
    for (int j = 0; j < 16; ++j) {
        int p = gi * 16 + j;
        if (p < N) {
            int n = perm[p];
            int d = rp[n + 1] - rp[n];
            m = m > d ? m : d;
        }
    }
    int L = (m + 3) & ~3;
    gL[gi] = L;
    gBase[gi] = L ? atomicAdd(cnt, 16 * L) : 0;
}

// Fill padded packed edge array: one WAVE per perm-position, {col,val} pairs,
// zero-padded to L.
__global__ __launch_bounds__(256) void fill_packed(
    const int* __restrict__ rp, const int* __restrict__ colIdx,
    const float* __restrict__ vals, const int* __restrict__ perm,
    const int* __restrict__ gL, const int* __restrict__ gBase,
    float2* __restrict__ packed, int N, int Npos) {
    int w = (blockIdx.x * 256 + threadIdx.x) >> 6;
    int lane = threadIdx.x & 63;
    if (w >= Npos) return;
    int gi = w >> 4;
    int L = gL[gi];
    if (L == 0) return;
    float2* dst = packed + (size_t)gBase[gi] + (size_t)(w & 15) * L;
    int d = 0, e0 = 0;
    if (w < N) {
        int n = perm[w];
        e0 = rp[n];
        d = rp[n + 1] - e0;
    }
    for (int j = lane; j < L; j += 64) {
        float2 v;
        if (j < d) {
            v.x = __int_as_float(colIdx[e0 + j]);
            v.y = vals[e0 + j];
        } else {
            v.x = __int_as_float(0);
            v.y = 0.f;
        }
        dst[j] = v;
    }
}

// ---------------------------------------------------------------------------
// One-shot W prep: all four W's -> bf16, transposed + XOR-swizzled.
// Layout: Wb[(n * (CIN/8) + (kc ^ (n&7))) * 8 + kr],  k = kc*8 + kr
// ---------------------------------------------------------------------------
__global__ __launch_bounds__(256) void wprep(
    const float* __restrict__ W1, const float* __restrict__ W2,
    const float* __restrict__ W3, const float* __restrict__ W4,
    unsigned short* __restrict__ B1, unsigned short* __restrict__ B2,
    unsigned short* __restrict__ B3, unsigned short* __restrict__ B4) {
    int i = blockIdx.x * 256 + threadIdx.x;
    const float* W;
    unsigned short* Wb;
    int CIN, COUT, idx;
    if (i < 32768) {
        W = W1; Wb = B1; CIN = 256; COUT = 128; idx = i;
    } else if (i < 49152) {
        W = W2; Wb = B2; CIN = 128; COUT = 128; idx = i - 32768;
    } else if (i < 57344) {
        W = W3; Wb = B3; CIN = 128; COUT = 64; idx = i - 49152;
    } else if (i < 59392) {
        W = W4; Wb = B4; CIN = 64; COUT = 32; idx = i - 57344;
    } else {
        return;
    }
    int k = idx / COUT, n = idx % COUT;
    int kc = k >> 3, kr = k & 7;
    Wb[((size_t)n * (CIN / 8) + (kc ^ (n & 7))) * 8 + kr] =
        (unsigned short)f2b(W[idx]);
}

// ---------------------------------------------------------------------------
// MFMA GEMM with fused input-BN. 256 threads, 64 rows/block.
// W staged in TWO COUT-halves (halves LDS -> more blocks/CU).
// ---------------------------------------------------------------------------
template <int CIN, int COUT, bool NORM>
__global__ __launch_bounds__(256) void gemm_mfma(
    float* H, const unsigned short* __restrict__ Wb,
    unsigned short* __restrict__ S, const float* __restrict__ st, float invN,
    int Nrows) {
    constexpr int CHALF = COUT / 2;
    constexpr int NCHUNK = CIN / 8;
    __shared__ short Wt[CIN * CHALF];

    int wave = threadIdx.x >> 6, lane = threadIdx.x & 63;
    int m = lane & 15, quad = lane >> 4;
    int r0 = blockIdx.x * 64 + wave * 16;
    int rowi = r0 + m;
    int rowc = rowi < Nrows ? rowi : (Nrows - 1);

    short8 a[CIN / 32];
    const float* hrow = H + (size_t)rowc * CIN;
#pragma unroll
    for (int ks = 0; ks < CIN / 32; ++ks) {
        int c0 = ks * 32 + quad * 8;
        const float* p = hrow + c0;
        floatx4 x0 = *(const floatx4*)p;
        floatx4 x1 = *(const floatx4*)(p + 4);
        if constexpr (NORM) {
            floatx4 s0 = *(const floatx4*)(st + c0);
            floatx4 s1 = *(const floatx4*)(st + c0 + 4);
            floatx4 q0 = *(const floatx4*)(st + CIN + c0);
            floatx4 q1 = *(const floatx4*)(st + CIN + c0 + 4);
#pragma unroll
            for (int j = 0; j < 4; ++j) {
                float mean = s0[j] * invN;
                float var = q0[j] * invN - mean * mean;
                x0[j] = (x0[j] - mean) * rsqrtf(fmaxf(var, 0.f) + 1e-5f);
                mean = s1[j] * invN;
                var = q1[j] * invN - mean * mean;
                x1[j] = (x1[j] - mean) * rsqrtf(fmaxf(var, 0.f) + 1e-5f);
            }
            if (rowi < Nrows) {
                float* op = H + (size_t)rowi * CIN + c0;
                __builtin_nontemporal_store(x0, (floatx4*)op);
                __builtin_nontemporal_store(x1, (floatx4*)(op + 4));
            }
        }
        short8 t;
#pragma unroll
        for (int j = 0; j < 4; ++j) {
            t[j] = (short)f2b(x0[j]);
            t[4 + j] = (short)f2b(x1[j]);
        }
        a[ks] = t;
    }

#pragma unroll
    for (int h = 0; h < 2; ++h) {
        {
            constexpr int CHUNKS = CIN * CHALF / 8;  // short8 chunks
            const short8* src = (const short8*)(Wb + h * CIN * CHALF);
            short8* dst = (short8*)Wt;
            for (int i = threadIdx.x; i < CHUNKS; i += 256) dst[i] = src[i];
        }
        __syncthreads();

#pragma unroll
        for (int nt = 0; nt < CHALF / 16; ++nt) {
            floatx4 acc = {0.f, 0.f, 0.f, 0.f};
            int nn = nt * 16 + m;  // local col within half
#pragma unroll
            for (int ks = 0; ks < CIN / 32; ++ks) {
                int kc = ks * 4 + quad;
                short8 b =
                    *(const short8*)(&Wt[(nn * NCHUNK + (kc ^ (nn & 7))) * 8]);
                acc = __builtin_amdgcn_mfma_f32_16x16x32_bf16(a[ks], b, acc, 0,
                                                              0, 0);
            }
            int n = h * CHALF + nn;
#pragma unroll
            for (int reg = 0; reg < 4; ++reg) {
                int rr = r0 + quad * 4 + reg;
                if (rr < Nrows) S[(size_t)rr * COUT + n] = f2b(acc[reg]);
            }
        }
        __syncthreads();
    }
}

// ---------------------------------------------------------------------------
// SpMM + activation + fused BN stats on the padded/binned edge layout.
// Wave-uniform row length (per 16-group), packed {col,val} 8B stream,
// zero clamps/selects. 2-slot wave-private LDS pipeline w/ counted vmcnt.
// ---------------------------------------------------------------------------
template <int C>
__global__ __launch_bounds__(256) void spmm_act_stats(
    const char* __restrict__ Sb, const float2* __restrict__ packed,
    const int* __restrict__ gBase, const int* __restrict__ gL,
    const int* __restrict__ perm, float* __restrict__ Ag,
    float* __restrict__ stats, int N, int Npos) {
    constexpr int LPN = C / 8;      // lanes per node
    constexpr int NPB = 256 / LPN;  // positions per block
    constexpr int SH = (C == 128) ? 8 : (C == 64) ? 7 : 6;  // row byte shift
    __shared__ __align__(16) char stage[4 * 2 * 4096];  // 4 waves x 2 slots

    int tid = threadIdx.x;
    int wave = tid >> 6, lane = tid & 63;
    int sub = tid / LPN, lc = tid % LPN;
    char* wbase = stage + wave * 8192;
    int lcoff = lc * 16;

    float s[8], s2[8];
#pragma unroll
    for (int j = 0; j < 8; ++j) { s[j] = 0.f; s2[j] = 0.f; }

    int nblk = (Npos + NPB - 1) / NPB;
    for (int blk = blockIdx.x; blk < nblk; blk += gridDim.x) {
        int p = blk * NPB + sub;
        int inb = p < Npos;                 // uniform per wave (16-aligned)
        int gi = inb ? (p >> 4) : 0;
        int L = inb ? gL[gi] : 0;           // uniform per wave
        float acc[8];
#pragma unroll
        for (int j = 0; j < 8; ++j) acc[j] = 0.f;

        if (L) {
            const float2* pe =
                packed + (size_t)gBase[gi] + (size_t)(p & 15) * L;
            int tmax = L >> 2;

            // prologue: pkA = batch0, pkB = batch1, issue gathers0 -> slot0
            float2 pkA[4], pkB[4];
#pragma unroll
            for (int k = 0; k < 4; ++k) pkA[k] = pe[k];
#pragma unroll
            for (int k = 0; k < 4; ++k) pkB[k] = pe[4 + k];
            SB();
#pragma unroll
            for (int k = 0; k < 4; ++k)
                gload16(Sb + (((unsigned)__float_as_uint(pkA[k].x) << SH) +
                              lcoff),
                        wbase + k * 1024);
            SB();

            // steady: iter t computes batch t, prefetches pk[t+2], gathers[t+1]
            for (int t = 0; t < tmax - 1; ++t) {
                int slot = t & 1;
                float2 pkC[4];
                const float2* pe2 = pe + t * 4 + 8;
#pragma unroll
                for (int k = 0; k < 4; ++k) pkC[k] = pe2[k];
                SB();
                WAITVM(8);  // retire pk[t+1] (pkB); gathers[t] still in flight
                char* dst = wbase + (slot ^ 1) * 4096;
#pragma unroll
                for (int k = 0; k < 4; ++k)
                    gload16(Sb + (((unsigned)__float_as_uint(pkB[k].x) << SH) +
                                  lcoff),
                            dst + k * 1024);
                SB();
                WAITVM(8);  // retire gathers[t]; {pkC, gathers[t+1]} in flight
                const char* src = wbase + slot * 4096 + lane * 16;
#pragma unroll
                for (int k = 0; k < 4; ++k) {
                    ushortx8 gk = *(const ushortx8*)(src + k * 1024);
                    float v = pkA[k].y;
#pragma unroll
                    for (int j = 0; j < 8; ++j) acc[j] += v * b2f(gk[j]);
                }
#pragma unroll
                for (int k = 0; k < 4; ++k) { pkA[k] = pkB[k]; pkB[k] = pkC[k]; }
            }

            // tail: compute last batch
            WAITVM(0);
            {
                int slot = (tmax - 1) & 1;
                const char* src = wbase + slot * 4096 + lane * 16;
#pragma unroll
                for (int k = 0; k < 4; ++k) {
                    ushortx8 gk = *(const ushortx8*)(src + k * 1024);
                    float v = pkA[k].y;
#pragma unroll
                    for (int j = 0; j < 8; ++j) acc[j] += v * b2f(gk[j]);
                }
            }
        }

        if (p < N) {
            int node = perm[p];
            floatx4 r0, r1;
#pragma unroll
            for (int j = 0; j < 4; ++j) {
                float a0 = act_elu_lrelu(acc[j]);
                float a1 = act_elu_lrelu(acc[4 + j]);
                r0[j] = a0;
                r1[j] = a1;
                s[j] += a0;
                s2[j] += a0 * a0;
                s[4 + j] += a1;
                s2[4 + j] += a1 * a1;
            }
            float* op = Ag + (size_t)node * C + lc * 8;
            *(floatx4*)op = r0;
            *(floatx4*)(op + 4) = r1;
        }
    }

    // block-level column reduce (reuse staging LDS; all waves done)
    __syncthreads();
    float* sh = (float*)stage;  // [2][NPB][C] = 16KB <= 32KB
#pragma unroll
    for (int j = 0; j < 8; ++j) {
        sh[(0 * NPB + sub) * C + lc * 8 + j] = s[j];
        sh[(1 * NPB + sub) * C + lc * 8 + j] = s2[j];
    }
    __syncthreads();
    if (tid < C) {
        float t0 = 0.f, t1 = 0.f;
        for (int gg = 0; gg < NPB; ++gg) {
            t0 += sh[(0 * NPB + gg) * C + tid];
            t1 += sh[(1 * NPB + gg) * C + tid];
        }
        atomicAdd(&stats[tid], t0);
        atomicAdd(&stats[C + tid], t1);
    }
}

// ---------------------------------------------------------------------------
// Final-layer BN normalize in place
// ---------------------------------------------------------------------------
template <int C>
__global__ __launch_bounds__(256) void bn_norm(
    float* __restrict__ Ag, const float* __restrict__ stats, int N) {
    constexpr int RPB = 256 / C;
    int c = threadIdx.x % C;
    int rg = threadIdx.x / C;
    float invN = 1.f / (float)N;
    float mean = stats[c] * invN;
    float var = stats[C + c] * invN - mean * mean;
    float inv = rsqrtf(fmaxf(var, 0.f) + 1e-5f);
    for (int r = blockIdx.x * RPB + rg; r < N; r += gridDim.x * RPB) {
        float x = Ag[(size_t)r * C + c];
        Ag[(size_t)r * C + c] = (x - mean) * inv;
    }
}

// ---------------------------------------------------------------------------
extern "C" void kernel_launch(void* const* d_in, const int* in_sizes, int n_in,
                              void* d_out, int out_size, void* d_ws,
                              size_t ws_size, hipStream_t stream) {
    const float* x = (const float*)d_in[0];
    const int* adj_row = (const int*)d_in[1];
    const int* adj_col = (const int*)d_in[2];
    const float* adj_vals = (const float*)d_in[3];
    const float* W1 = (const float*)d_in[4];
    const float* W2 = (const float*)d_in[5];
    const float* W3 = (const float*)d_in[6];
    const float* W4 = (const float*)d_in[7];

    int N = in_sizes[0] / 256;
    int E = in_sizes[1];
    int ngroups = (N + 15) / 16;
    int Npos = ngroups * 16;

    // workspace carve
    char* ws = (char*)d_ws;
    size_t off = 0;
    auto carve = [&](size_t bytes) {
        char* p = ws + off;
        off = (off + bytes + 255) & ~(size_t)255;
        return p;
    };
    int* rp = (int*)carve((size_t)(N + 1) * 4);
    // contiguous memset region: stats(1024f) + hist(256i) + cnt(64i)
    float* stats = (float*)carve((1024 + 256 + 64) * 4);
    int* hist = (int*)((char*)stats + 1024 * 4);
    int* cnt = hist + 256;
    int* binCur = (int*)carve(256 * 4);
    unsigned short* Wb1 = (unsigned short*)carve(32768 * 2);
    unsigned short* Wb2 = (unsigned short*)carve(16384 * 2);
    unsigned short* Wb3 = (unsigned short*)carve(8192 * 2);
    unsigned short* Wb4 = (unsigned short*)carve(2048 * 2);
    int* perm = (int*)carve((size_t)Npos * 4);
    int* gL = (int*)carve((size_t)ngroups * 4);
    int* gBase = (int*)carve((size_t)ngroups * 4);
    float2* packed = (float2*)carve(((size_t)E + 4 * (size_t)N + 2048) * 8);
    unsigned short* S = (unsigned short*)carve((size_t)N * 128 * 2);

    hipMemsetAsync(stats, 0, (1024 + 256 + 64) * 4, stream);
    build_rowptr<<<(E + 255) / 256, 256, 0, stream>>>(adj_row, rp, E, N);
    wprep<<<232, 256, 0, stream>>>(W1, W2, W3, W4, Wb1, Wb2, Wb3, Wb4);
    int nb = (N + 255) / 256;
    deg_hist<<<nb, 256, 0, stream>>>(rp, hist, N);
    scan256<<<1, 256, 0, stream>>>(hist, binCur);
    deg_scatter<<<nb, 256, 0, stream>>>(rp, binCur, perm, N);
    grp_len<<<(ngroups + 255) / 256, 256, 0, stream>>>(rp, perm, gL, gBase,
                                                       cnt, N, ngroups);
    fill_packed<<<(Npos + 3) / 4, 256, 0, stream>>>(
        rp, adj_col, adj_vals, perm, gL, gBase, packed, N, Npos);

    float* h1 = (float*)d_out;
    float* h2 = h1 + (size_t)N * 128;
    float* h3 = h2 + (size_t)N * 128;
    float* h4 = h3 + (size_t)N * 64;

    float invN = 1.f / (float)N;
    int gblk = (N + 63) / 64;
    auto sgrid = [&](int npb) {
        int ng = (Npos + npb - 1) / npb;
        return ng < 2048 ? ng : 2048;
    };

    // layer 1: 256 -> 128 (input x is not normalized)
    gemm_mfma<256, 128, false><<<gblk, 256, 0, stream>>>(
        (float*)x, Wb1, S, nullptr, invN, N);
    spmm_act_stats<128><<<sgrid(16), 256, 0, stream>>>(
        (const char*)S, packed, gBase, gL, perm, h1, stats + 0, N, Npos);

    // layer 2: 128 -> 128 (gemm normalizes h1 in place using stats0)
    gemm_mfma<128, 128, true><<<gblk, 256, 0, stream>>>(
        h1, Wb2, S, stats + 0, invN, N);
    spmm_act_stats<128><<<sgrid(16), 256, 0, stream>>>(
        (const char*)S, packed, gBase, gL, perm, h2, stats + 256, N, Npos);

    // layer 3: 128 -> 64
    gemm_mfma<128, 64, true><<<gblk, 256, 0, stream>>>(
        h2, Wb3, S, stats + 256, invN, N);
    spmm_act_stats<64><<<sgrid(32), 256, 0, stream>>>(
        (const char*)S, packed, gBase, gL, perm, h3, stats + 512, N, Npos);

    // layer 4: 64 -> 32
    gemm_mfma<64, 32, true><<<gblk, 256, 0, stream>>>(
        h3, Wb4, S, stats + 512, invN, N);
    spmm_act_stats<32><<<sgrid(64), 256, 0, stream>>>(
        (const char*)S, packed, gBase, gL, perm, h4, stats + 768, N, Npos);
    bn_norm<32><<<256, 256, 0, stream>>>(h4, stats + 768, N);
}